// Round 5
// baseline (101.271 us; speedup 1.0000x reference)
//
#include <hip/hip_runtime.h>
#include <hip/hip_bf16.h>

typedef __bf16 bf16x8 __attribute__((ext_vector_type(8)));
typedef float  f32x16 __attribute__((ext_vector_type(16)));
typedef unsigned int u32;

constexpr int QN  = 128;   // query rows
constexpr int KN  = 2048;  // memory rows
constexpr int D5  = 768;
constexpr int ZD  = 24;    // per-token sub-dim
constexpr int KCH = 8;     // k's per block (2 per wave)

static __device__ __forceinline__ float max3f(float a, float b, float c) {
    return fmaxf(fmaxf(a, b), c);   // fuses to v_max3_f32
}

static __device__ __forceinline__ float redmax16(const f32x16& a) {
    float x0 = max3f(a[0],  a[1],  a[2]);
    float x1 = max3f(a[3],  a[4],  a[5]);
    float x2 = max3f(a[6],  a[7],  a[8]);
    float x3 = max3f(a[9],  a[10], a[11]);
    float x4 = max3f(a[12], a[13], a[14]);
    float y0 = max3f(x0, x1, x2);
    float y1 = max3f(x3, x4, a[15]);
    return fmaxf(y0, y1);
}

// R5: DS-pipe diet. Each wave owns 2 k's and all 4 q's -> K fragments read from
// LDS ONCE per wave (4 ds_read_b128 total, was 16); Q fragments in registers
// from global. Per-pair epilogue: NO shfl -- both halves pack (m1,m2) as
// 2xbf16 into one dword and ds_write_b32 (fire-and-forget); batched epilogue
// does half-max + sums via vector ds_read_b128 (XOR-swizzled, conflict-free).
__global__ __launch_bounds__(256, 3) void matcher_kernel(const float* __restrict__ tgt,
                                                         const float* __restrict__ mem,
                                                         float* __restrict__ out)
{
    // Per k: chunk0 = 64 lanes x 16B (d0-15), chunk1 = 64 lanes x 16B (d16-23 + zero pad).
    __shared__ __align__(16) __bf16 Kf[KCH * 1024];    // 16 KB
    // Per-wave packed-max buffer: 8 pairs x 64 words.
    __shared__ __align__(16) u32 vbuf[4 * 512];        // 8 KB (total 24 KB)

    const int tid = threadIdx.x;
    const int kc  = blockIdx.x;   // 0..255
    const int qg  = blockIdx.y;   // 0..31
    const int k0  = kc * KCH;

    // ---- stage K chunk: fp32 -> bf16, MFMA fragment order (one item/thread) ----
    {
        const int kl = tid >> 5;
        const int s  = tid & 31;
        const float* src = mem + (size_t)(k0 + kl) * D5 + s * ZD;
        float tv[24];
#pragma unroll
        for (int j = 0; j < 6; ++j) ((float4*)tv)[j] = ((const float4*)src)[j];
        bf16x8 a, b, c, z;
#pragma unroll
        for (int j = 0; j < 8; ++j) {
            a[j] = (__bf16)tv[j];
            b[j] = (__bf16)tv[8 + j];
            c[j] = (__bf16)tv[16 + j];
            z[j] = (__bf16)0.0f;
        }
        __bf16* base = Kf + kl * 1024;
        *(bf16x8*)(base +        s * 8)       = a;  // chunk0, lane s      (d 0-7)
        *(bf16x8*)(base + (32 +  s) * 8)      = b;  // chunk0, lane s+32   (d 8-15)
        *(bf16x8*)(base + 512 +  s * 8)       = c;  // chunk1, lane s      (d 16-23)
        *(bf16x8*)(base + 512 + (32 + s) * 8) = z;  // chunk1, lane s+32   (pad)
    }

    const int lane = tid & 63;
    const int wv   = tid >> 6;   // 0..3
    const int t    = lane & 31;
    const int h    = lane >> 5;

    // ---- Q fragments for ALL 4 q's of this block (registers, from global) ----
    bf16x8 aQ0[4], aQ1[4];
#pragma unroll
    for (int qq = 0; qq < 4; ++qq) {
        const int q = qg * 4 + qq;
        const float4* p4 = (const float4*)(tgt + (size_t)q * D5 + t * ZD);
        float4 u0 = p4[2 * h], u1 = p4[2 * h + 1];  // d = h*8 .. h*8+7
        aQ0[qq][0] = (__bf16)u0.x; aQ0[qq][1] = (__bf16)u0.y;
        aQ0[qq][2] = (__bf16)u0.z; aQ0[qq][3] = (__bf16)u0.w;
        aQ0[qq][4] = (__bf16)u1.x; aQ0[qq][5] = (__bf16)u1.y;
        aQ0[qq][6] = (__bf16)u1.z; aQ0[qq][7] = (__bf16)u1.w;
        if (h == 0) {
            float4 w0 = p4[4], w1 = p4[5];          // d = 16..23
            aQ1[qq][0] = (__bf16)w0.x; aQ1[qq][1] = (__bf16)w0.y;
            aQ1[qq][2] = (__bf16)w0.z; aQ1[qq][3] = (__bf16)w0.w;
            aQ1[qq][4] = (__bf16)w1.x; aQ1[qq][5] = (__bf16)w1.y;
            aQ1[qq][6] = (__bf16)w1.z; aQ1[qq][7] = (__bf16)w1.w;
        } else {
#pragma unroll
            for (int j = 0; j < 8; ++j) aQ1[qq][j] = (__bf16)0.0f; // d 24-31 pad
        }
    }

    f32x16 zacc;
#pragma unroll
    for (int i = 0; i < 16; ++i) zacc[i] = 0.0f;

    __syncthreads();

    // ---- this wave's 2 k's: K fragments read from LDS ONCE ----
    bf16x8 bK0[2], bK1[2];
#pragma unroll
    for (int j = 0; j < 2; ++j) {
        const __bf16* base = Kf + (wv * 2 + j) * 1024 + lane * 8;
        bK0[j] = *(const bf16x8*)base;
        bK1[j] = *(const bf16x8*)(base + 512);
    }

    u32* vbw = vbuf + wv * 512;
    const int cbase = h * 32;   // half offset within a pair's 64-word segment

    // ---- 8 pairs (4 q x 2 k), fully unrolled, all-register MFMA operands ----
#pragma unroll
    for (int p = 0; p < 8; ++p) {
        const int qq = p >> 1, j = p & 1;
        // S[t][s]: A=Q (m=t), B=K (n=s)
        f32x16 accS = __builtin_amdgcn_mfma_f32_32x32x16_bf16(aQ0[qq], bK0[j], zacc, 0, 0, 0);
        accS        = __builtin_amdgcn_mfma_f32_32x32x16_bf16(aQ1[qq], bK1[j], accS, 0, 0, 0);
        // S^T[s][t]: A=K (m=s), B=Q (n=t)
        f32x16 accT = __builtin_amdgcn_mfma_f32_32x32x16_bf16(bK0[j], aQ0[qq], zacc, 0, 0, 0);
        accT        = __builtin_amdgcn_mfma_f32_32x32x16_bf16(bK1[j], aQ1[qq], accT, 0, 0, 0);

        // per-lane partial maxes: m1 = max over this half's t-rows at s=lane&31
        //                         m2 = max over this half's s-rows at t=lane&31
        float m1 = redmax16(accS);
        float m2 = redmax16(accT);
        // pack as 2xbf16 (truncate): error ~0.01 on pooled mean, sigmoid-saturated
        u32 pk = (__float_as_uint(m1) & 0xFFFF0000u) | (__float_as_uint(m2) >> 16);
        // XOR-swizzled slot (conflict-free: lanes 0-31 permute banks; +32 aliases 2-way = free)
        vbw[p * 64 + cbase + (t ^ ((4 * p) & 31))] = pk;
    }

    // ---- batched epilogue (same wave; no barrier needed) ----
    {
        const int p = lane >> 3;         // pair 0..7
        const int e = lane & 7;          // 8 lanes per pair, 4 columns each
        const u32* g = vbw + p * 64 + ((4 * e) ^ ((4 * p) & 31));
        uint4 g0 = *(const uint4*)g;          // half0, cols 4e..4e+3 (order preserved)
        uint4 g1 = *(const uint4*)(g + 32);   // half1, same cols
        u32 w0[4] = {g0.x, g0.y, g0.z, g0.w};
        u32 w1[4] = {g1.x, g1.y, g1.z, g1.w};
        float sum = 0.0f;
#pragma unroll
        for (int i = 0; i < 4; ++i) {
            float a1 = __uint_as_float(w0[i] & 0xFFFF0000u);  // m1, half0
            float a2 = __uint_as_float(w0[i] << 16);          // m2, half0
            float b1 = __uint_as_float(w1[i] & 0xFFFF0000u);  // m1, half1
            float b2 = __uint_as_float(w1[i] << 16);          // m2, half1
            sum += fmaxf(a1, b1) + fmaxf(a2, b2);
        }
        sum += __shfl_xor(sum, 1);
        sum += __shfl_xor(sum, 2);
        sum += __shfl_xor(sum, 4);       // total over the pair's 32 columns
        float r = 1.0f / (1.0f + __expf(-sum * (1.0f / 64.0f)));
        if (e == 0) {
            const int q  = qg * 4 + (p >> 1);
            const int kk = k0 + wv * 2 + (p & 1);
            const int idx = q * KN + kk;
            out[idx] = r;                 // output 0
            out[idx + QN * KN] = r;       // output 1 (tuple repeats score_p)
        }
    }
}

extern "C" void kernel_launch(void* const* d_in, const int* in_sizes, int n_in,
                              void* d_out, int out_size, void* d_ws, size_t ws_size,
                              hipStream_t stream)
{
    const float* tgt = (const float*)d_in[0];
    const float* mem = (const float*)d_in[1];
    float* out = (float*)d_out;
    dim3 grid(KN / KCH, QN / 4);
    matcher_kernel<<<grid, 256, 0, stream>>>(tgt, mem, out);
}